// Round 1
// baseline (1485.257 us; speedup 1.0000x reference)
//
#include <hip/hip_runtime.h>
#include <hip/hip_bf16.h>
#include <stdint.h>

typedef __bf16 bf16_t;
typedef __attribute__((ext_vector_type(8))) __bf16 bf16x8;
typedef __attribute__((ext_vector_type(4))) float f32x4;

#define RMS_EPS 1e-6f

// ---------------- constants for this problem ----------------
// B=8, N=2048, D=1024, C=1024, H=4096; BN = B*N = 16384
#define DIM_D 1024
#define DIM_C 1024
#define DIM_H 4096
#define DIM_BN 16384
#define SEQ_N 2048

// ---------------- rmsnorm + cast to bf16 (D=1024, block=256) ----------------
__global__ __launch_bounds__(256) void rmsnorm_cast_kernel(
    const float* __restrict__ x, const float* __restrict__ g,
    bf16_t* __restrict__ out) {
  const int row = blockIdx.x;
  const float* xr = x + (size_t)row * DIM_D;
  bf16_t* orow = out + (size_t)row * DIM_D;
  const int tid = threadIdx.x;
  float4 v = ((const float4*)xr)[tid];
  float ss = v.x * v.x + v.y * v.y + v.z * v.z + v.w * v.w;
  for (int off = 32; off > 0; off >>= 1) ss += __shfl_down(ss, off);
  __shared__ float wsum[4];
  const int wave = tid >> 6, lane = tid & 63;
  if (lane == 0) wsum[wave] = ss;
  __syncthreads();
  const float tot = wsum[0] + wsum[1] + wsum[2] + wsum[3];
  const float inv = rsqrtf(tot * (1.0f / DIM_D) + RMS_EPS);
  float4 gv = ((const float4*)g)[tid];
  union { bf16_t h[4]; uint2 u; } o;
  o.h[0] = (bf16_t)(v.x * inv * gv.x);
  o.h[1] = (bf16_t)(v.y * inv * gv.y);
  o.h[2] = (bf16_t)(v.z * inv * gv.z);
  o.h[3] = (bf16_t)(v.w * inv * gv.w);
  *(uint2*)&orow[tid * 4] = o.u;
}

// ---------------- transpose fp32 [R,Cc] -> bf16 [Cc,R] ----------------
__global__ void transpose_cast_kernel(const float* __restrict__ in,
                                      bf16_t* __restrict__ out, int R, int Cc) {
  __shared__ float tile[32][33];
  const int bx = blockIdx.x * 32;  // col base
  const int by = blockIdx.y * 32;  // row base
  const int tx = threadIdx.x, ty = threadIdx.y;  // (32,8)
#pragma unroll
  for (int i = 0; i < 32; i += 8)
    tile[ty + i][tx] = in[(size_t)(by + ty + i) * Cc + bx + tx];
  __syncthreads();
#pragma unroll
  for (int i = 0; i < 32; i += 8)
    out[(size_t)(bx + ty + i) * R + by + tx] = (bf16_t)tile[tx][ty + i];
}

// ---------------- RoPE fp32 [rows,D] -> bf16 [rows,D] ----------------
__global__ __launch_bounds__(256) void rope_cast_kernel(
    const float* __restrict__ x, const int* __restrict__ pos,
    bf16_t* __restrict__ out) {
  const int row = blockIdx.x;
  const float p = (float)pos[row];
  const float* xr = x + (size_t)row * DIM_D;
  bf16_t* orow = out + (size_t)row * DIM_D;
  const int tid = threadIdx.x;
  const float lg = 0.0179889035f;  // ln(10000)/512
#pragma unroll
  for (int t = 0; t < 2; t++) {
    const int i = tid + t * 256;  // pair index 0..511
    const float invf = expf(-(float)i * lg);
    const float ang = p * invf;
    float s, c;
    sincosf(ang, &s, &c);
    float2 x12 = ((const float2*)xr)[i];
    union { bf16_t h[2]; uint32_t u; } o;
    o.h[0] = (bf16_t)(x12.x * c - x12.y * s);
    o.h[1] = (bf16_t)(x12.x * s + x12.y * c);
    *(uint32_t*)&orow[2 * i] = o.u;
  }
}

// ---------------- gumbel: lat = (la + gns * gumbel(u)) / tau ----------------
__global__ __launch_bounds__(256) void gumbel_kernel(
    const float* __restrict__ la, const float* __restrict__ un,
    const float* __restrict__ tau_p, const float* __restrict__ gns_p,
    float* __restrict__ lat) {
  const size_t i = blockIdx.x * 256ull + threadIdx.x;
  const float inv_tau = 1.0f / tau_p[0];
  const float gns = gns_p[0];
  float4 u = ((const float4*)un)[i];
  float4 a = ((const float4*)la)[i];
  float4 o;
  o.x = (a.x + gns * (-logf(-logf(u.x + 1e-10f) + 1e-10f))) * inv_tau;
  o.y = (a.y + gns * (-logf(-logf(u.y + 1e-10f) + 1e-10f))) * inv_tau;
  o.z = (a.z + gns * (-logf(-logf(u.z + 1e-10f) + 1e-10f))) * inv_tau;
  o.w = (a.w + gns * (-logf(-logf(u.w + 1e-10f) + 1e-10f))) * inv_tau;
  ((float4*)lat)[i] = o;
}

// ---------------- row softmax over C=1024; writes z fp32 + z bf16 ----------------
__global__ __launch_bounds__(256) void softmax_kernel(
    const float* __restrict__ lat, float* __restrict__ z,
    bf16_t* __restrict__ zb) {
  const int row = blockIdx.x;
  const float* xr = lat + (size_t)row * DIM_C;
  const int tid = threadIdx.x;
  float4 v = ((const float4*)xr)[tid];
  float mx = fmaxf(fmaxf(v.x, v.y), fmaxf(v.z, v.w));
  for (int off = 32; off > 0; off >>= 1) mx = fmaxf(mx, __shfl_down(mx, off));
  __shared__ float sm[4];
  __shared__ float ssum[4];
  const int wave = tid >> 6, lane = tid & 63;
  if (lane == 0) sm[wave] = mx;
  __syncthreads();
  mx = fmaxf(fmaxf(sm[0], sm[1]), fmaxf(sm[2], sm[3]));
  float4 e;
  e.x = __expf(v.x - mx);
  e.y = __expf(v.y - mx);
  e.z = __expf(v.z - mx);
  e.w = __expf(v.w - mx);
  float s = e.x + e.y + e.z + e.w;
  for (int off = 32; off > 0; off >>= 1) s += __shfl_down(s, off);
  if (lane == 0) ssum[wave] = s;
  __syncthreads();
  const float inv = 1.0f / (ssum[0] + ssum[1] + ssum[2] + ssum[3]);
  float4 o;
  o.x = e.x * inv; o.y = e.y * inv; o.z = e.z * inv; o.w = e.w * inv;
  ((float4*)(z + (size_t)row * DIM_C))[tid] = o;
  union { bf16_t h[4]; uint2 u; } ob;
  ob.h[0] = (bf16_t)o.x; ob.h[1] = (bf16_t)o.y;
  ob.h[2] = (bf16_t)o.z; ob.h[3] = (bf16_t)o.w;
  *(uint2*)&zb[(size_t)row * DIM_C + tid * 4] = ob.u;
}

// ---------------- GEMM: C[M,N] = A[M,K] @ Bt[N,K]^T  (bf16 in, fp32 acc) --------
// MODE 0: Cf = acc
// MODE 1: Cf = acc + auxf[n]                  (bias)
// MODE 2: Cf = acc * scale                    (log_alpha)
// MODE 3: Cb = bf16(acc)
// MODE 4: Cf = sc_ptr[0]*auxf[idx] + acc      (residual: attn_out)
// MODE 5: Cb = bf16(silu(auxb[idx]) * acc)    (swiglu; auxb may alias Cb)
// MODE 6: Cf = auxf[idx] + acc                (final add)
template <int MODE>
__global__ __launch_bounds__(256, 2) void gemm_bt(
    const bf16_t* __restrict__ A, const bf16_t* __restrict__ Bt,
    int M, int N, int K,
    float* __restrict__ Cf, bf16_t* __restrict__ Cb,
    const float* __restrict__ auxf, const bf16_t* __restrict__ auxb,
    const float* __restrict__ sc_ptr, float scale) {
  __shared__ __align__(16) bf16_t As[128 * 32];
  __shared__ __align__(16) bf16_t Bs[128 * 32];
  const int tid = threadIdx.x;
  const int lane = tid & 63;
  const int wave = tid >> 6;
  const int wm = (wave >> 1) * 64;
  const int wn = (wave & 1) * 64;
  const int bm0 = blockIdx.y * 128;
  const int bn0 = blockIdx.x * 128;
  const int r4 = tid >> 2;        // staging row 0..63
  const int c4 = (tid & 3) * 8;   // staging k-chunk
  const int quad = lane >> 4;
  const int l16 = lane & 15;

  f32x4 acc[4][4];
#pragma unroll
  for (int i = 0; i < 4; i++)
#pragma unroll
    for (int j = 0; j < 4; j++) acc[i][j] = (f32x4){0.f, 0.f, 0.f, 0.f};

  for (int k0 = 0; k0 < K; k0 += 32) {
#pragma unroll
    for (int h = 0; h < 2; h++) {
      const int row = r4 + h * 64;
      *(uint4*)&As[row * 32 + c4] =
          *(const uint4*)&A[(size_t)(bm0 + row) * K + k0 + c4];
      *(uint4*)&Bs[row * 32 + c4] =
          *(const uint4*)&Bt[(size_t)(bn0 + row) * K + k0 + c4];
    }
    __syncthreads();
    bf16x8 af[4], bfr[4];
#pragma unroll
    for (int i = 0; i < 4; i++)
      af[i] = *(const bf16x8*)&As[(wm + i * 16 + l16) * 32 + quad * 8];
#pragma unroll
    for (int j = 0; j < 4; j++)
      bfr[j] = *(const bf16x8*)&Bs[(wn + j * 16 + l16) * 32 + quad * 8];
#pragma unroll
    for (int i = 0; i < 4; i++)
#pragma unroll
      for (int j = 0; j < 4; j++)
        acc[i][j] = __builtin_amdgcn_mfma_f32_16x16x32_bf16(af[i], bfr[j],
                                                            acc[i][j], 0, 0, 0);
    __syncthreads();
  }

  float rs = 0.f;
  if (MODE == 4) rs = sc_ptr[0];
#pragma unroll
  for (int i = 0; i < 4; i++) {
#pragma unroll
    for (int j = 0; j < 4; j++) {
      const int n = bn0 + wn + j * 16 + l16;
#pragma unroll
      for (int r = 0; r < 4; r++) {
        const int m = bm0 + wm + i * 16 + quad * 4 + r;
        const size_t idx = (size_t)m * N + n;
        const float v = acc[i][j][r];
        if (MODE == 0) {
          Cf[idx] = v;
        } else if (MODE == 1) {
          Cf[idx] = v + auxf[n];
        } else if (MODE == 2) {
          Cf[idx] = v * scale;
        } else if (MODE == 3) {
          Cb[idx] = (bf16_t)v;
        } else if (MODE == 4) {
          Cf[idx] = rs * auxf[idx] + v;
        } else if (MODE == 5) {
          const float u = (float)auxb[idx];
          const float su = u / (1.0f + __expf(-u));
          Cb[idx] = (bf16_t)(su * v);
        } else if (MODE == 6) {
          Cf[idx] = auxf[idx] + v;
        }
      }
    }
  }
}

// ---------------- launch ----------------
extern "C" void kernel_launch(void* const* d_in, const int* in_sizes, int n_in,
                              void* d_out, int out_size, void* d_ws,
                              size_t ws_size, hipStream_t stream) {
  const float* latents  = (const float*)d_in[0];
  const float* codebook = (const float*)d_in[1];
  const float* Wq = (const float*)d_in[2];
  const float* Wk = (const float*)d_in[3];
  const float* Wv = (const float*)d_in[4];
  const float* bv = (const float*)d_in[5];
  const float* Wc = (const float*)d_in[6];
  const float* w1 = (const float*)d_in[7];
  const float* w2 = (const float*)d_in[8];
  const float* w3 = (const float*)d_in[9];
  const float* g_ctx = (const float*)d_in[10];
  const float* g_q = (const float*)d_in[11];
  const float* g_ff = (const float*)d_in[12];
  const float* un = (const float*)d_in[13];
  const int* positions = (const int*)d_in[14];
  const float* tau = (const float*)d_in[15];
  const float* rs = (const float*)d_in[16];
  const float* gns = (const float*)d_in[17];

  float* out = (float*)d_out;
  const size_t OFF_LA  = 16777216;       // B*N*D
  const size_t OFF_LAT = 2 * 16777216ull;
  const size_t OFF_Z   = 3 * 16777216ull;

  char* wsb = (char*)d_ws;
  // byte offsets (all 16B-aligned)
  bf16_t* wqT = (bf16_t*)(wsb + 0);            // 2MB
  bf16_t* wkT = (bf16_t*)(wsb + 2097152);      // 2MB
  bf16_t* wvT = (bf16_t*)(wsb + 4194304);      // 2MB
  bf16_t* wcT = (bf16_t*)(wsb + 6291456);      // 2MB
  bf16_t* w1T = (bf16_t*)(wsb + 8388608);      // 8MB
  bf16_t* w3T = (bf16_t*)(wsb + 16777216);     // 8MB
  bf16_t* w2T = (bf16_t*)(wsb + 25165824);     // 8MB
  bf16_t* nctx = (bf16_t*)(wsb + 33554432);    // 2MB
  float*  kf  = (float*)(wsb + 35651584);      // 4MB
  float*  vf  = (float*)(wsb + 39845888);      // 4MB
  bf16_t* kR  = (bf16_t*)(wsb + 44040192);     // 2MB
  bf16_t* vT  = (bf16_t*)(wsb + 46137344);     // 2MB
  bf16_t* nq  = (bf16_t*)(wsb + 48234496);     // 32MB (later reused: z bf16)
  bf16_t* zb  = nq;
  float*  qf  = (float*)(wsb + 81788928);      // 64MB (later reused: attn_out)
  float*  attn_out = qf;
  bf16_t* qR  = (bf16_t*)(wsb + 148897792);    // 32MB (later reused: attn bf16)
  bf16_t* attn_b = qR;
  bf16_t* hbuf = (bf16_t*)(wsb + 182452224);   // 32MB
  bf16_t* ug  = (bf16_t*)(wsb + 216006656);    // 32MB (u then g, in place)

  const dim3 tb32(32, 8);

  // weight transposes (fp32 -> bf16 [N,K] layouts)
  transpose_cast_kernel<<<dim3(32, 32), tb32, 0, stream>>>(Wq, wqT, 1024, 1024);
  transpose_cast_kernel<<<dim3(32, 32), tb32, 0, stream>>>(Wk, wkT, 1024, 1024);
  transpose_cast_kernel<<<dim3(32, 32), tb32, 0, stream>>>(Wv, wvT, 1024, 1024);
  transpose_cast_kernel<<<dim3(32, 32), tb32, 0, stream>>>(Wc, wcT, 1024, 1024);
  transpose_cast_kernel<<<dim3(128, 32), tb32, 0, stream>>>(w1, w1T, 1024, 4096);
  transpose_cast_kernel<<<dim3(128, 32), tb32, 0, stream>>>(w3, w3T, 1024, 4096);
  transpose_cast_kernel<<<dim3(32, 128), tb32, 0, stream>>>(w2, w2T, 4096, 1024);

  // rmsnorms
  rmsnorm_cast_kernel<<<DIM_C, 256, 0, stream>>>(codebook, g_ctx, nctx);
  rmsnorm_cast_kernel<<<DIM_BN, 256, 0, stream>>>(latents, g_q, nq);

  // k, v, q projections (fp32 out)
  gemm_bt<0><<<dim3(8, 8), 256, 0, stream>>>(nctx, wkT, 1024, 1024, 1024, kf,
                                             nullptr, nullptr, nullptr, nullptr, 0.f);
  gemm_bt<1><<<dim3(8, 8), 256, 0, stream>>>(nctx, wvT, 1024, 1024, 1024, vf,
                                             nullptr, bv, nullptr, nullptr, 0.f);
  gemm_bt<0><<<dim3(8, 128), 256, 0, stream>>>(nq, wqT, DIM_BN, 1024, 1024, qf,
                                               nullptr, nullptr, nullptr, nullptr, 0.f);

  // rope + casts
  rope_cast_kernel<<<DIM_BN, 256, 0, stream>>>(qf, positions, qR);
  rope_cast_kernel<<<DIM_C, 256, 0, stream>>>(kf, positions, kR);
  transpose_cast_kernel<<<dim3(32, 32), tb32, 0, stream>>>(vf, vT, 1024, 1024);

  // log_alpha = qR @ kR^T / 32  -> d_out
  gemm_bt<2><<<dim3(8, 128), 256, 0, stream>>>(qR, kR, DIM_BN, DIM_C, 1024,
                                               out + OFF_LA, nullptr, nullptr,
                                               nullptr, nullptr, 0.03125f);
  // log_alpha_tau -> d_out
  gumbel_kernel<<<16384, 256, 0, stream>>>(out + OFF_LA, un, tau, gns,
                                           out + OFF_LAT);
  // softmax -> z fp32 (d_out) + z bf16 (ws)
  softmax_kernel<<<DIM_BN, 256, 0, stream>>>(out + OFF_LAT, out + OFF_Z, zb);

  // attn = z @ v  (bf16 out)
  gemm_bt<3><<<dim3(8, 128), 256, 0, stream>>>(zb, vT, DIM_BN, 1024, 1024,
                                               nullptr, attn_b, nullptr, nullptr,
                                               nullptr, 0.f);
  // attn_out = rs*latents + attn @ Wc
  gemm_bt<4><<<dim3(8, 128), 256, 0, stream>>>(attn_b, wcT, DIM_BN, 1024, 1024,
                                               attn_out, nullptr, latents,
                                               nullptr, rs, 0.f);
  // h = rmsnorm(attn_out) * g_ff
  rmsnorm_cast_kernel<<<DIM_BN, 256, 0, stream>>>(attn_out, g_ff, hbuf);

  // FFN in 4 row-chunks of 4096
  for (int r0 = 0; r0 < DIM_BN; r0 += 4096) {
    const bf16_t* hc = hbuf + (size_t)r0 * DIM_D;
    gemm_bt<3><<<dim3(32, 32), 256, 0, stream>>>(hc, w1T, 4096, DIM_H, 1024,
                                                 nullptr, ug, nullptr, nullptr,
                                                 nullptr, 0.f);
    gemm_bt<5><<<dim3(32, 32), 256, 0, stream>>>(hc, w3T, 4096, DIM_H, 1024,
                                                 nullptr, ug, nullptr, ug,
                                                 nullptr, 0.f);
    gemm_bt<6><<<dim3(8, 32), 256, 0, stream>>>(ug, w2T, 4096, DIM_D, DIM_H,
                                                out + (size_t)r0 * DIM_D,
                                                nullptr,
                                                attn_out + (size_t)r0 * DIM_D,
                                                nullptr, nullptr, 0.f);
  }
}

// Round 2
// 1458.048 us; speedup vs baseline: 1.0187x; 1.0187x over previous
//
#include <hip/hip_runtime.h>
#include <hip/hip_bf16.h>
#include <stdint.h>

typedef __bf16 bf16_t;
typedef __attribute__((ext_vector_type(8))) __bf16 bf16x8;
typedef __attribute__((ext_vector_type(4))) float f32x4;

#define RMS_EPS 1e-6f

// B=8, N=2048, D=1024, C=1024, H=4096; BN = B*N = 16384
#define DIM_D 1024
#define DIM_C 1024
#define DIM_H 4096
#define DIM_BN 16384

// async 16B global->LDS copy; lds_base must be the wave-uniform chunk base,
// HW writes lane l's 16B at lds_base + l*16 (m104/m108 semantics).
__device__ __forceinline__ void async_copy16(const bf16_t* gsrc,
                                             bf16_t* lds_base) {
  __builtin_amdgcn_global_load_lds(
      (const __attribute__((address_space(1))) uint32_t*)gsrc,
      (__attribute__((address_space(3))) uint32_t*)lds_base, 16, 0, 0);
}

// ---------------- rmsnorm + cast to bf16 (D=1024, block=256) ----------------
__global__ __launch_bounds__(256) void rmsnorm_cast_kernel(
    const float* __restrict__ x, const float* __restrict__ g,
    bf16_t* __restrict__ out) {
  const int row = blockIdx.x;
  const float* xr = x + (size_t)row * DIM_D;
  bf16_t* orow = out + (size_t)row * DIM_D;
  const int tid = threadIdx.x;
  float4 v = ((const float4*)xr)[tid];
  float ss = v.x * v.x + v.y * v.y + v.z * v.z + v.w * v.w;
  for (int off = 32; off > 0; off >>= 1) ss += __shfl_down(ss, off);
  __shared__ float wsum[4];
  const int wave = tid >> 6, lane = tid & 63;
  if (lane == 0) wsum[wave] = ss;
  __syncthreads();
  const float tot = wsum[0] + wsum[1] + wsum[2] + wsum[3];
  const float inv = rsqrtf(tot * (1.0f / DIM_D) + RMS_EPS);
  float4 gv = ((const float4*)g)[tid];
  union { bf16_t h[4]; uint2 u; } o;
  o.h[0] = (bf16_t)(v.x * inv * gv.x);
  o.h[1] = (bf16_t)(v.y * inv * gv.y);
  o.h[2] = (bf16_t)(v.z * inv * gv.z);
  o.h[3] = (bf16_t)(v.w * inv * gv.w);
  *(uint2*)&orow[tid * 4] = o.u;
}

// ---------------- transpose fp32 [R,Cc] -> bf16 [Cc,R] ----------------
__global__ void transpose_cast_kernel(const float* __restrict__ in,
                                      bf16_t* __restrict__ out, int R, int Cc) {
  __shared__ float tile[32][33];
  const int bx = blockIdx.x * 32;  // col base
  const int by = blockIdx.y * 32;  // row base
  const int tx = threadIdx.x, ty = threadIdx.y;  // (32,8)
#pragma unroll
  for (int i = 0; i < 32; i += 8)
    tile[ty + i][tx] = in[(size_t)(by + ty + i) * Cc + bx + tx];
  __syncthreads();
#pragma unroll
  for (int i = 0; i < 32; i += 8)
    out[(size_t)(bx + ty + i) * R + by + tx] = (bf16_t)tile[tx][ty + i];
}

// ---------------- RoPE fp32 [rows,D] -> bf16 [rows,D] ----------------
__global__ __launch_bounds__(256) void rope_cast_kernel(
    const float* __restrict__ x, const int* __restrict__ pos,
    bf16_t* __restrict__ out) {
  const int row = blockIdx.x;
  const float p = (float)pos[row];
  const float* xr = x + (size_t)row * DIM_D;
  bf16_t* orow = out + (size_t)row * DIM_D;
  const int tid = threadIdx.x;
  const float lg = 0.0179889035f;  // ln(10000)/512
#pragma unroll
  for (int t = 0; t < 2; t++) {
    const int i = tid + t * 256;  // pair index 0..511
    const float invf = expf(-(float)i * lg);
    const float ang = p * invf;
    float s, c;
    sincosf(ang, &s, &c);
    float2 x12 = ((const float2*)xr)[i];
    union { bf16_t h[2]; uint32_t u; } o;
    o.h[0] = (bf16_t)(x12.x * c - x12.y * s);
    o.h[1] = (bf16_t)(x12.x * s + x12.y * c);
    *(uint32_t*)&orow[2 * i] = o.u;
  }
}

// ---------------- row softmax over C=1024; writes z fp32 + z bf16 ----------------
__global__ __launch_bounds__(256) void softmax_kernel(
    const float* __restrict__ lat, float* __restrict__ z,
    bf16_t* __restrict__ zb) {
  const int row = blockIdx.x;
  const float* xr = lat + (size_t)row * DIM_C;
  const int tid = threadIdx.x;
  float4 v = ((const float4*)xr)[tid];
  float mx = fmaxf(fmaxf(v.x, v.y), fmaxf(v.z, v.w));
  for (int off = 32; off > 0; off >>= 1) mx = fmaxf(mx, __shfl_down(mx, off));
  __shared__ float sm[4];
  __shared__ float ssum[4];
  const int wave = tid >> 6, lane = tid & 63;
  if (lane == 0) sm[wave] = mx;
  __syncthreads();
  mx = fmaxf(fmaxf(sm[0], sm[1]), fmaxf(sm[2], sm[3]));
  float4 e;
  e.x = __expf(v.x - mx);
  e.y = __expf(v.y - mx);
  e.z = __expf(v.z - mx);
  e.w = __expf(v.w - mx);
  float s = e.x + e.y + e.z + e.w;
  for (int off = 32; off > 0; off >>= 1) s += __shfl_down(s, off);
  if (lane == 0) ssum[wave] = s;
  __syncthreads();
  const float inv = 1.0f / (ssum[0] + ssum[1] + ssum[2] + ssum[3]);
  float4 o;
  o.x = e.x * inv; o.y = e.y * inv; o.z = e.z * inv; o.w = e.w * inv;
  ((float4*)(z + (size_t)row * DIM_C))[tid] = o;
  union { bf16_t h[4]; uint2 u; } ob;
  ob.h[0] = (bf16_t)o.x; ob.h[1] = (bf16_t)o.y;
  ob.h[2] = (bf16_t)o.z; ob.h[3] = (bf16_t)o.w;
  *(uint2*)&zb[(size_t)row * DIM_C + tid * 4] = ob.u;
}

// ---------------- GEMM: C[M,N] = A[M,K] @ Bt[N,K]^T  (bf16 in, fp32 acc) --------
// MODE 0: Cf = acc
// MODE 1: Cf = acc + auxf[n]                  (bias)
// MODE 3: Cb = bf16(acc)
// MODE 4: Cf = sc_ptr[0]*auxf[idx] + acc      (residual: attn_out)
// MODE 5: Cb = bf16(silu(auxb[idx]) * acc)    (swiglu; auxb may alias Cb)
// MODE 6: Cf = auxf[idx] + acc                (final add)
// MODE 7: la = acc*scale; Cf = la; Cf2 = (la + gns*gumbel(auxf[idx]))/tau
//         (sc_ptr = gns, sc2_ptr = tau, auxf = uniform_noise)
template <int MODE>
__global__ __launch_bounds__(256, 2) void gemm_bt(
    const bf16_t* __restrict__ A, const bf16_t* __restrict__ Bt,
    int M, int N, int K,
    float* __restrict__ Cf, bf16_t* __restrict__ Cb,
    const float* __restrict__ auxf, const bf16_t* __restrict__ auxb,
    const float* __restrict__ sc_ptr, const float* __restrict__ sc2_ptr,
    float* __restrict__ Cf2, float scale) {
  __shared__ __align__(16) bf16_t As[128 * 32];
  __shared__ __align__(16) bf16_t Bs[128 * 32];
  const int tid = threadIdx.x;
  const int lane = tid & 63;
  const int wave = tid >> 6;
  const int wm = (wave >> 1) * 64;
  const int wn = (wave & 1) * 64;
  const int bm0 = blockIdx.y * 128;
  const int bn0 = blockIdx.x * 128;
  const int quad = lane >> 4;
  const int l16 = lane & 15;
  // staging: wave w, chunk h covers rows [(h*4+w)*16, +16); lane l -> byte l*16
  const int srow = lane >> 2;        // row within 16-row chunk
  const int scol = (lane & 3) * 8;   // k-offset (bf16 elems)

  f32x4 acc[4][4];
#pragma unroll
  for (int i = 0; i < 4; i++)
#pragma unroll
    for (int j = 0; j < 4; j++) acc[i][j] = (f32x4){0.f, 0.f, 0.f, 0.f};

  for (int k0 = 0; k0 < K; k0 += 32) {
#pragma unroll
    for (int h = 0; h < 2; h++) {
      const int chunk = h * 4 + wave;
      const int row = chunk * 16 + srow;
      async_copy16(&A[(size_t)(bm0 + row) * K + k0 + scol], &As[chunk * 512]);
      async_copy16(&Bt[(size_t)(bn0 + row) * K + k0 + scol], &Bs[chunk * 512]);
    }
    __syncthreads();
    bf16x8 af[4], bfr[4];
#pragma unroll
    for (int i = 0; i < 4; i++)
      af[i] = *(const bf16x8*)&As[(wm + i * 16 + l16) * 32 + quad * 8];
#pragma unroll
    for (int j = 0; j < 4; j++)
      bfr[j] = *(const bf16x8*)&Bs[(wn + j * 16 + l16) * 32 + quad * 8];
#pragma unroll
    for (int i = 0; i < 4; i++)
#pragma unroll
      for (int j = 0; j < 4; j++)
        acc[i][j] = __builtin_amdgcn_mfma_f32_16x16x32_bf16(af[i], bfr[j],
                                                            acc[i][j], 0, 0, 0);
    __syncthreads();
  }

  float rs = 0.f, inv_tau = 0.f, gns = 0.f;
  if (MODE == 4) rs = sc_ptr[0];
  if (MODE == 7) { gns = sc_ptr[0]; inv_tau = 1.0f / sc2_ptr[0]; }
#pragma unroll
  for (int i = 0; i < 4; i++) {
#pragma unroll
    for (int j = 0; j < 4; j++) {
      const int n = bn0 + wn + j * 16 + l16;
#pragma unroll
      for (int r = 0; r < 4; r++) {
        const int m = bm0 + wm + i * 16 + quad * 4 + r;
        const size_t idx = (size_t)m * N + n;
        const float v = acc[i][j][r];
        if (MODE == 0) {
          Cf[idx] = v;
        } else if (MODE == 1) {
          Cf[idx] = v + auxf[n];
        } else if (MODE == 3) {
          Cb[idx] = (bf16_t)v;
        } else if (MODE == 4) {
          Cf[idx] = rs * auxf[idx] + v;
        } else if (MODE == 5) {
          const float u = (float)auxb[idx];
          const float su = u / (1.0f + __expf(-u));
          Cb[idx] = (bf16_t)(su * v);
        } else if (MODE == 6) {
          Cf[idx] = auxf[idx] + v;
        } else if (MODE == 7) {
          const float la = v * scale;
          Cf[idx] = la;
          const float u = auxf[idx];
          const float gmb = -logf(-logf(u + 1e-10f) + 1e-10f);
          Cf2[idx] = (la + gns * gmb) * inv_tau;
        }
      }
    }
  }
}

// ---------------- launch ----------------
extern "C" void kernel_launch(void* const* d_in, const int* in_sizes, int n_in,
                              void* d_out, int out_size, void* d_ws,
                              size_t ws_size, hipStream_t stream) {
  const float* latents  = (const float*)d_in[0];
  const float* codebook = (const float*)d_in[1];
  const float* Wq = (const float*)d_in[2];
  const float* Wk = (const float*)d_in[3];
  const float* Wv = (const float*)d_in[4];
  const float* bv = (const float*)d_in[5];
  const float* Wc = (const float*)d_in[6];
  const float* w1 = (const float*)d_in[7];
  const float* w2 = (const float*)d_in[8];
  const float* w3 = (const float*)d_in[9];
  const float* g_ctx = (const float*)d_in[10];
  const float* g_q = (const float*)d_in[11];
  const float* g_ff = (const float*)d_in[12];
  const float* un = (const float*)d_in[13];
  const int* positions = (const int*)d_in[14];
  const float* tau = (const float*)d_in[15];
  const float* rs = (const float*)d_in[16];
  const float* gns = (const float*)d_in[17];

  float* out = (float*)d_out;
  const size_t OFF_LA  = 16777216;       // B*N*D
  const size_t OFF_LAT = 2 * 16777216ull;
  const size_t OFF_Z   = 3 * 16777216ull;

  char* wsb = (char*)d_ws;
  bf16_t* wqT = (bf16_t*)(wsb + 0);            // 2MB
  bf16_t* wkT = (bf16_t*)(wsb + 2097152);      // 2MB
  bf16_t* wvT = (bf16_t*)(wsb + 4194304);      // 2MB
  bf16_t* wcT = (bf16_t*)(wsb + 6291456);      // 2MB
  bf16_t* w1T = (bf16_t*)(wsb + 8388608);      // 8MB
  bf16_t* w3T = (bf16_t*)(wsb + 16777216);     // 8MB
  bf16_t* w2T = (bf16_t*)(wsb + 25165824);     // 8MB
  bf16_t* nctx = (bf16_t*)(wsb + 33554432);    // 2MB
  float*  kf  = (float*)(wsb + 35651584);      // 4MB
  float*  vf  = (float*)(wsb + 39845888);      // 4MB
  bf16_t* kR  = (bf16_t*)(wsb + 44040192);     // 2MB
  bf16_t* vT  = (bf16_t*)(wsb + 46137344);     // 2MB
  bf16_t* nq  = (bf16_t*)(wsb + 48234496);     // 32MB (later reused: z bf16)
  bf16_t* zb  = nq;
  float*  qf  = (float*)(wsb + 81788928);      // 64MB (later reused: attn_out)
  float*  attn_out = qf;
  bf16_t* qR  = (bf16_t*)(wsb + 148897792);    // 32MB (later reused: attn bf16)
  bf16_t* attn_b = qR;
  bf16_t* hbuf = (bf16_t*)(wsb + 182452224);   // 32MB
  bf16_t* ug  = (bf16_t*)(wsb + 216006656);    // 32MB (u then g, in place)

  const dim3 tb32(32, 8);

  // weight transposes (fp32 -> bf16 [N,K] layouts)
  transpose_cast_kernel<<<dim3(32, 32), tb32, 0, stream>>>(Wq, wqT, 1024, 1024);
  transpose_cast_kernel<<<dim3(32, 32), tb32, 0, stream>>>(Wk, wkT, 1024, 1024);
  transpose_cast_kernel<<<dim3(32, 32), tb32, 0, stream>>>(Wv, wvT, 1024, 1024);
  transpose_cast_kernel<<<dim3(32, 32), tb32, 0, stream>>>(Wc, wcT, 1024, 1024);
  transpose_cast_kernel<<<dim3(128, 32), tb32, 0, stream>>>(w1, w1T, 1024, 4096);
  transpose_cast_kernel<<<dim3(128, 32), tb32, 0, stream>>>(w3, w3T, 1024, 4096);
  transpose_cast_kernel<<<dim3(32, 128), tb32, 0, stream>>>(w2, w2T, 4096, 1024);

  // rmsnorms
  rmsnorm_cast_kernel<<<DIM_C, 256, 0, stream>>>(codebook, g_ctx, nctx);
  rmsnorm_cast_kernel<<<DIM_BN, 256, 0, stream>>>(latents, g_q, nq);

  // k, v, q projections (fp32 out)
  gemm_bt<0><<<dim3(8, 8), 256, 0, stream>>>(nctx, wkT, 1024, 1024, 1024, kf,
                                             nullptr, nullptr, nullptr, nullptr,
                                             nullptr, nullptr, 0.f);
  gemm_bt<1><<<dim3(8, 8), 256, 0, stream>>>(nctx, wvT, 1024, 1024, 1024, vf,
                                             nullptr, bv, nullptr, nullptr,
                                             nullptr, nullptr, 0.f);
  gemm_bt<0><<<dim3(8, 128), 256, 0, stream>>>(nq, wqT, DIM_BN, 1024, 1024, qf,
                                               nullptr, nullptr, nullptr, nullptr,
                                               nullptr, nullptr, 0.f);

  // rope + casts
  rope_cast_kernel<<<DIM_BN, 256, 0, stream>>>(qf, positions, qR);
  rope_cast_kernel<<<DIM_C, 256, 0, stream>>>(kf, positions, kR);
  transpose_cast_kernel<<<dim3(32, 32), tb32, 0, stream>>>(vf, vT, 1024, 1024);

  // log_alpha (-> d_out) and log_alpha_tau (-> d_out) fused in epilogue
  gemm_bt<7><<<dim3(8, 128), 256, 0, stream>>>(qR, kR, DIM_BN, DIM_C, 1024,
                                               out + OFF_LA, nullptr, un,
                                               nullptr, gns, tau,
                                               out + OFF_LAT, 0.03125f);
  // softmax -> z fp32 (d_out) + z bf16 (ws)
  softmax_kernel<<<DIM_BN, 256, 0, stream>>>(out + OFF_LAT, out + OFF_Z, zb);

  // attn = z @ v  (bf16 out)
  gemm_bt<3><<<dim3(8, 128), 256, 0, stream>>>(zb, vT, DIM_BN, 1024, 1024,
                                               nullptr, attn_b, nullptr, nullptr,
                                               nullptr, nullptr, nullptr, 0.f);
  // attn_out = rs*latents + attn @ Wc
  gemm_bt<4><<<dim3(8, 128), 256, 0, stream>>>(attn_b, wcT, DIM_BN, 1024, 1024,
                                               attn_out, nullptr, latents,
                                               nullptr, rs, nullptr, nullptr, 0.f);
  // h = rmsnorm(attn_out) * g_ff
  rmsnorm_cast_kernel<<<DIM_BN, 256, 0, stream>>>(attn_out, g_ff, hbuf);

  // FFN in 4 row-chunks of 4096
  for (int r0 = 0; r0 < DIM_BN; r0 += 4096) {
    const bf16_t* hc = hbuf + (size_t)r0 * DIM_D;
    gemm_bt<3><<<dim3(32, 32), 256, 0, stream>>>(hc, w1T, 4096, DIM_H, 1024,
                                                 nullptr, ug, nullptr, nullptr,
                                                 nullptr, nullptr, nullptr, 0.f);
    gemm_bt<5><<<dim3(32, 32), 256, 0, stream>>>(hc, w3T, 4096, DIM_H, 1024,
                                                 nullptr, ug, nullptr, ug,
                                                 nullptr, nullptr, nullptr, 0.f);
    gemm_bt<6><<<dim3(8, 32), 256, 0, stream>>>(ug, w2T, 4096, DIM_D, DIM_H,
                                                out + (size_t)r0 * DIM_D,
                                                nullptr,
                                                attn_out + (size_t)r0 * DIM_D,
                                                nullptr, nullptr, nullptr,
                                                nullptr, 0.f);
  }
}